// Round 1
// baseline (599.695 us; speedup 1.0000x reference)
//
#include <hip/hip_runtime.h>
#include <stdint.h>

typedef unsigned short u16;
typedef __bf16 bf16_t;
typedef bf16_t bf16x8 __attribute__((ext_vector_type(8)));
typedef float f32x4 __attribute__((ext_vector_type(4)));
typedef u16 u16x4 __attribute__((ext_vector_type(4)));

__device__ __forceinline__ u16 f2bf(float f) {
  union { float f; uint32_t u; } v;
  v.f = f;
  uint32_t u = v.u + 0x7fffu + ((v.u >> 16) & 1u);
  return (u16)(u >> 16);
}

__device__ __forceinline__ void gload16(const void* g, void* l) {
  __builtin_amdgcn_global_load_lds(
      (__attribute__((address_space(1))) void*)g,
      (__attribute__((address_space(3))) void*)l, 16, 0, 0);
}

__device__ __forceinline__ f32x4 mfma16(bf16x8 a, bf16x8 b, f32x4 c) {
  return __builtin_amdgcn_mfma_f32_16x16x32_bf16(a, b, c, 0, 0, 0);
}

// ---------------- fp32 -> bf16 convert ----------------
__global__ void cvt_f32_bf16(const float* __restrict__ in, u16* __restrict__ out, int n4) {
  int i = blockIdx.x * blockDim.x + threadIdx.x;
  int stride = gridDim.x * blockDim.x;
  for (; i < n4; i += stride) {
    float4 v = *((const float4*)in + i);
    u16x4 o;
    o.x = f2bf(v.x); o.y = f2bf(v.y); o.z = f2bf(v.z); o.w = f2bf(v.w);
    *((u16x4*)out + i) = o;
  }
}

// ---------------- weight transpose + convert: Wt[n][k] = (bf16)W[k][n] ----------------
__global__ void wt_transpose(const float* __restrict__ Wq, const float* __restrict__ Wk,
                             const float* __restrict__ Wv, u16* __restrict__ Oq,
                             u16* __restrict__ Ok, u16* __restrict__ Ov) {
  const float* W = blockIdx.z == 0 ? Wq : (blockIdx.z == 1 ? Wk : Wv);
  u16* O = blockIdx.z == 0 ? Oq : (blockIdx.z == 1 ? Ok : Ov);
  __shared__ float t[32][33];
  int x = threadIdx.x, y = threadIdx.y;
  int n0 = blockIdx.x * 32, k0 = blockIdx.y * 32;
#pragma unroll
  for (int i = 0; i < 32; i += 8)
    t[y + i][x] = W[(size_t)(k0 + y + i) * 1024 + n0 + x];
  __syncthreads();
#pragma unroll
  for (int i = 0; i < 32; i += 8)
    O[(size_t)(n0 + y + i) * 1024 + k0 + x] = f2bf(t[x][y + i]);
}

// ---------------- bf16 GEMM: C[M][N] = A[M][K] * Bt[N][K]^T + bias ----------------
__global__ __launch_bounds__(256, 2) void gemm_bt(
    const u16* __restrict__ A, const u16* __restrict__ Bt,
    const float* __restrict__ biasRow, const float* __restrict__ biasCol,
    u16* __restrict__ C, int M, int N) {
  const int K = 1024;
  __shared__ u16 aL[128 * 64];
  __shared__ u16 bL[128 * 64];
  int tid = threadIdx.x;
  int lane = tid & 63, w = tid >> 6;
  int l15 = lane & 15, g = lane >> 4;
  int bm = blockIdx.x * 128, bn = blockIdx.y * 128;
  int wm = (w >> 1) * 64, wn = (w & 1) * 64;
  f32x4 acc[4][4] = {};

  for (int k0 = 0; k0 < K; k0 += 64) {
    __syncthreads();
#pragma unroll
    for (int r = 0; r < 4; ++r) {
      int ub = r * 256 + w * 64;
      int u = ub + lane;
      int row = u >> 3, d = (u & 7) * 8;
      gload16(A + (size_t)(bm + row) * K + k0 + d, aL + ub * 8);
      gload16(Bt + (size_t)(bn + row) * K + k0 + d, bL + ub * 8);
    }
    __syncthreads();
#pragma unroll
    for (int kc = 0; kc < 2; ++kc) {
      bf16x8 af[4], bfv[4];
#pragma unroll
      for (int i = 0; i < 4; ++i)
        af[i] = *(const bf16x8*)(aL + (wm + i * 16 + l15) * 64 + kc * 32 + g * 8);
#pragma unroll
      for (int j = 0; j < 4; ++j)
        bfv[j] = *(const bf16x8*)(bL + (wn + j * 16 + l15) * 64 + kc * 32 + g * 8);
#pragma unroll
      for (int i = 0; i < 4; ++i)
#pragma unroll
        for (int j = 0; j < 4; ++j)
          acc[i][j] = mfma16(af[i], bfv[j], acc[i][j]);
    }
  }
#pragma unroll
  for (int i = 0; i < 4; ++i) {
    int row = bm + wm + i * 16 + g * 4;
#pragma unroll
    for (int j = 0; j < 4; ++j) {
      int col = bn + wn + j * 16 + l15;
      float bc = biasCol ? biasCol[col] : 0.0f;
#pragma unroll
      for (int rr = 0; rr < 4; ++rr) {
        float br = biasRow ? biasRow[row + rr] : 0.0f;
        C[(size_t)(row + rr) * N + col] = f2bf(acc[i][j][rr] + bc + br);
      }
    }
  }
}

// ---------------- fused flash attention ----------------
// grid (64, 4): x = q-block of 32 rows, y = batch. 512 threads = 8 waves.
// wave w: qband = w>>2 (16 q-rows), kvband = w&3 (16 kv-cols) for QK^T;
// wave w owns out-cols [w*128, w*128+128) for PV.
__global__ __launch_bounds__(512, 2) void attn_fused(
    const u16* __restrict__ Qg, const u16* __restrict__ Kg,
    const u16* __restrict__ VTg, const float* __restrict__ mask,
    float* __restrict__ out) {
  __shared__ u16 qL[32 * 1024];       // swizzled Q tile
  __shared__ u16 pL[32 * 80];         // P tile bf16, padded stride 80
  __shared__ float pmaxL[2][4][16];
  __shared__ float psumL[2][4][16];
  __shared__ float mstate[32], lstate[32], scaleL[32];

  const float C1 = 0.04508422f;        // (1/32)*log2(e)
  const float C2 = -1.4426950e9f;      // -1e9*log2(e)

  int tid = threadIdx.x;
  int lane = tid & 63, w = tid >> 6;
  int l15 = lane & 15, g = lane >> 4;
  int qband = w >> 2, kvband = w & 3;
  int q0 = blockIdx.x * 32;
  int b = blockIdx.y;
  size_t bofs = (size_t)b * 2048;

  if (tid < 32) { mstate[tid] = -__builtin_inff(); lstate[tid] = 0.0f; }

  // stage Q tile (32 x 1024 bf16), XOR-swizzle 16B-unit index low 3 bits by row&7,
  // applied on the GLOBAL source so the linear global_load_lds dest ends up swizzled.
  {
    size_t gq0 = bofs + q0;
#pragma unroll
    for (int r = 0; r < 8; ++r) {
      int ub = r * 512 + w * 64;
      int u = ub + lane;
      int row = u >> 7, d = u & 127;
      int sd = d ^ (row & 7);
      gload16(Qg + ((gq0 + row) << 10) + sd * 8, qL + ub * 8);
    }
  }
  __syncthreads();

  f32x4 o[2][8] = {};
  int qrow = qband * 16 + l15;
  int rs = qrow & 7;

  for (int it = 0; it < 32; ++it) {
    int kv0 = it * 64;
    // ---- QK^T: S[16q x 16kv] per wave, D=1024 ----
    f32x4 s0 = {}, s1 = {};
    const u16* kp = Kg + (bofs + kv0 + kvband * 16 + l15) * 1024 + g * 8;
#pragma unroll 8
    for (int t = 0; t < 32; ++t) {
      bf16x8 qa = *(const bf16x8*)(qL + qrow * 1024 + (((t * 4 + g) ^ rs) * 8));
      bf16x8 kb = *(const bf16x8*)(kp + t * 32);
      if (t & 1) s1 = mfma16(qa, kb, s1); else s0 = mfma16(qa, kb, s0);
    }
    f32x4 sv = s0 + s1;

    // ---- scale + mask (base-2 domain) ----
    const float* mp = mask + (bofs + q0 + qband * 16 + g * 4) * 2048 + kv0 + kvband * 16 + l15;
    float s2[4], p[4], tm[4];
#pragma unroll
    for (int rr = 0; rr < 4; ++rr) {
      s2[rr] = sv[rr] * C1 + mp[(size_t)rr * 2048] * C2;
      tm[rr] = s2[rr];
    }
#pragma unroll
    for (int m = 1; m < 16; m <<= 1) {
#pragma unroll
      for (int rr = 0; rr < 4; ++rr) tm[rr] = fmaxf(tm[rr], __shfl_xor(tm[rr], m));
    }
    if (l15 == 0) {
#pragma unroll
      for (int rr = 0; rr < 4; ++rr) pmaxL[qband][kvband][g * 4 + rr] = tm[rr];
    }
    __syncthreads();  // A: pmax visible

    float mnew[4], sf[4], ts[4];
#pragma unroll
    for (int rr = 0; rr < 4; ++rr) {
      int row = g * 4 + rr;
      float tmax = fmaxf(fmaxf(pmaxL[qband][0][row], pmaxL[qband][1][row]),
                         fmaxf(pmaxL[qband][2][row], pmaxL[qband][3][row]));
      float mold = mstate[qband * 16 + row];
      float mn = fmaxf(mold, tmax);
      mnew[rr] = mn;
      sf[rr] = exp2f(mold - mn);
      p[rr] = exp2f(s2[rr] - mn);
      ts[rr] = p[rr];
    }
#pragma unroll
    for (int m = 1; m < 16; m <<= 1) {
#pragma unroll
      for (int rr = 0; rr < 4; ++rr) ts[rr] += __shfl_xor(ts[rr], m);
    }
    __syncthreads();  // B: everyone done reading pmax/mstate

    if (l15 == 0) {
#pragma unroll
      for (int rr = 0; rr < 4; ++rr) psumL[qband][kvband][g * 4 + rr] = ts[rr];
      if (kvband == 0) {
#pragma unroll
        for (int rr = 0; rr < 4; ++rr) {
          mstate[qband * 16 + g * 4 + rr] = mnew[rr];
          scaleL[qband * 16 + g * 4 + rr] = sf[rr];
        }
      }
    }
#pragma unroll
    for (int rr = 0; rr < 4; ++rr)
      pL[(qband * 16 + g * 4 + rr) * 80 + kvband * 16 + l15] = f2bf(p[rr]);
    __syncthreads();  // C: psum/scale/P visible

    if (kvband == 0 && l15 == 0) {
#pragma unroll
      for (int rr = 0; rr < 4; ++rr) {
        int row = qband * 16 + g * 4 + rr;
        lstate[row] = lstate[row] * sf[rr] +
                      (psumL[qband][0][g * 4 + rr] + psumL[qband][1][g * 4 + rr]) +
                      (psumL[qband][2][g * 4 + rr] + psumL[qband][3][g * 4 + rr]);
      }
    }

    // ---- O rescale ----
#pragma unroll
    for (int qt = 0; qt < 2; ++qt) {
#pragma unroll
      for (int rr = 0; rr < 4; ++rr) {
        float sc = scaleL[qt * 16 + g * 4 + rr];
#pragma unroll
        for (int ct = 0; ct < 8; ++ct) o[qt][ct][rr] *= sc;
      }
    }

    // ---- PV: O[32q x 128cols/wave] += P[32 x 64] * V[64 x cols] ----
    const u16* vp = VTg + (size_t)(w * 128 + l15) * 8192 + bofs + kv0 + g * 8;
#pragma unroll
    for (int kvc = 0; kvc < 2; ++kvc) {
      bf16x8 pa0 = *(const bf16x8*)(pL + l15 * 80 + kvc * 32 + g * 8);
      bf16x8 pa1 = *(const bf16x8*)(pL + (16 + l15) * 80 + kvc * 32 + g * 8);
#pragma unroll
      for (int ct = 0; ct < 8; ++ct) {
        bf16x8 vb = *(const bf16x8*)(vp + (size_t)ct * 16 * 8192 + kvc * 32);
        o[0][ct] = mfma16(pa0, vb, o[0][ct]);
        o[1][ct] = mfma16(pa1, vb, o[1][ct]);
      }
    }
  }

  __syncthreads();  // lstate final
#pragma unroll
  for (int qt = 0; qt < 2; ++qt) {
#pragma unroll
    for (int rr = 0; rr < 4; ++rr) {
      int row = qt * 16 + g * 4 + rr;
      float inv = 1.0f / lstate[row];
      size_t obase = (bofs + q0 + row) * 1024 + w * 128 + l15;
#pragma unroll
      for (int ct = 0; ct < 8; ++ct)
        out[obase + (size_t)ct * 16] = o[qt][ct][rr] * inv;
    }
  }
}

extern "C" void kernel_launch(void* const* d_in, const int* in_sizes, int n_in,
                              void* d_out, int out_size, void* d_ws, size_t ws_size,
                              hipStream_t stream) {
  const float* primary = (const float*)d_in[0];
  const float* ctx     = (const float*)d_in[1];
  const float* mask    = (const float*)d_in[2];
  const float* Wq      = (const float*)d_in[3];
  const float* bq      = (const float*)d_in[4];
  const float* Wk      = (const float*)d_in[5];
  const float* bk      = (const float*)d_in[6];
  const float* Wv      = (const float*)d_in[7];
  const float* bv      = (const float*)d_in[8];
  float* out = (float*)d_out;

  char* ws = (char*)d_ws;
  u16* prim_bf = (u16*)(ws);
  u16* ctx_bf  = (u16*)(ws + 16777216);
  u16* wqt     = (u16*)(ws + 2 * 16777216);
  u16* wkt     = (u16*)(ws + 2 * 16777216 + 1 * 2097152);
  u16* wvt     = (u16*)(ws + 2 * 16777216 + 2 * 2097152);
  u16* qbf     = (u16*)(ws + 2 * 16777216 + 3 * 2097152);
  u16* kbf     = (u16*)(ws + 3 * 16777216 + 3 * 2097152);
  u16* vtbf    = (u16*)(ws + 4 * 16777216 + 3 * 2097152);

  cvt_f32_bf16<<<2048, 256, 0, stream>>>(primary, prim_bf, 8388608 / 4);
  cvt_f32_bf16<<<2048, 256, 0, stream>>>(ctx, ctx_bf, 8388608 / 4);
  wt_transpose<<<dim3(32, 32, 3), dim3(32, 8), 0, stream>>>(Wq, Wk, Wv, wqt, wkt, wvt);
  // Q = primary @ Wq + bq   (col bias)
  gemm_bt<<<dim3(64, 8), 256, 0, stream>>>(prim_bf, wqt, nullptr, bq, qbf, 8192, 1024);
  // K = ctx @ Wk + bk       (col bias)
  gemm_bt<<<dim3(64, 8), 256, 0, stream>>>(ctx_bf, wkt, nullptr, bk, kbf, 8192, 1024);
  // V^T = Wv^T @ ctx^T + bv (row bias) -> VT[n][b*2048+kv]
  gemm_bt<<<dim3(8, 64), 256, 0, stream>>>(wvt, ctx_bf, bv, nullptr, vtbf, 1024, 8192);
  attn_fused<<<dim3(64, 4), 512, 0, stream>>>(qbf, kbf, vtbf, mask, out);
}

// Round 2
// 264.541 us; speedup vs baseline: 2.2669x; 2.2669x over previous
//
#include <hip/hip_runtime.h>
#include <stdint.h>

typedef unsigned short u16;
typedef __bf16 bf16_t;
typedef bf16_t bf16x8 __attribute__((ext_vector_type(8)));
typedef float f32x4 __attribute__((ext_vector_type(4)));
typedef u16 u16x4 __attribute__((ext_vector_type(4)));
typedef u16 u16x8 __attribute__((ext_vector_type(8)));

__device__ __forceinline__ u16 f2bf(float f) {
  union { float f; uint32_t u; } v;
  v.f = f;
  uint32_t u = v.u + 0x7fffu + ((v.u >> 16) & 1u);
  return (u16)(u >> 16);
}

__device__ __forceinline__ float bf2f(u16 x) {
  union { uint32_t u; float f; } v;
  v.u = ((uint32_t)x) << 16;
  return v.f;
}

__device__ __forceinline__ void gload16(const void* g, void* l) {
  __builtin_amdgcn_global_load_lds(
      (__attribute__((address_space(1))) void*)g,
      (__attribute__((address_space(3))) void*)l, 16, 0, 0);
}

__device__ __forceinline__ f32x4 mfma16(bf16x8 a, bf16x8 b, f32x4 c) {
  return __builtin_amdgcn_mfma_f32_16x16x32_bf16(a, b, c, 0, 0, 0);
}

// ---------------- fp32 -> bf16 convert ----------------
__global__ void cvt_f32_bf16(const float* __restrict__ in, u16* __restrict__ out, int n4) {
  int i = blockIdx.x * blockDim.x + threadIdx.x;
  int stride = gridDim.x * blockDim.x;
  for (; i < n4; i += stride) {
    float4 v = *((const float4*)in + i);
    u16x4 o;
    o.x = f2bf(v.x); o.y = f2bf(v.y); o.z = f2bf(v.z); o.w = f2bf(v.w);
    *((u16x4*)out + i) = o;
  }
}

// ---------------- weight transpose + convert: Wt[n][k] = (bf16)W[k][n] ----------------
__global__ void wt_transpose(const float* __restrict__ Wq, const float* __restrict__ Wk,
                             const float* __restrict__ Wv, u16* __restrict__ Oq,
                             u16* __restrict__ Ok, u16* __restrict__ Ov) {
  const float* W = blockIdx.z == 0 ? Wq : (blockIdx.z == 1 ? Wk : Wv);
  u16* O = blockIdx.z == 0 ? Oq : (blockIdx.z == 1 ? Ok : Ov);
  __shared__ float t[32][33];
  int x = threadIdx.x, y = threadIdx.y;
  int n0 = blockIdx.x * 32, k0 = blockIdx.y * 32;
#pragma unroll
  for (int i = 0; i < 32; i += 8)
    t[y + i][x] = W[(size_t)(k0 + y + i) * 1024 + n0 + x];
  __syncthreads();
#pragma unroll
  for (int i = 0; i < 32; i += 8)
    O[(size_t)(n0 + y + i) * 1024 + k0 + x] = f2bf(t[x][y + i]);
}

// ---------------- bf16 GEMM: C[M][N] = A[M][K] * Bt[N][K]^T + bias ----------------
// Batched via blockIdx.z with element strides bsA/bsB/bsC. CT = u16 (bf16 out) or float.
template <typename CT>
__global__ __launch_bounds__(256, 2) void gemm_bt(
    const u16* __restrict__ A, const u16* __restrict__ Bt,
    const float* __restrict__ biasRow, const float* __restrict__ biasCol,
    CT* __restrict__ C, int M, int N, int K, int lda, int ldb, int ldc,
    long long bsA, long long bsB, long long bsC) {
  A += (size_t)blockIdx.z * bsA;
  Bt += (size_t)blockIdx.z * bsB;
  C += (size_t)blockIdx.z * bsC;
  __shared__ u16 aL[128 * 64];
  __shared__ u16 bL[128 * 64];
  int tid = threadIdx.x;
  int lane = tid & 63, w = tid >> 6;
  int l15 = lane & 15, g = lane >> 4;
  int bm = blockIdx.x * 128, bn = blockIdx.y * 128;
  int wm = (w >> 1) * 64, wn = (w & 1) * 64;
  f32x4 acc[4][4] = {};

  for (int k0 = 0; k0 < K; k0 += 64) {
    __syncthreads();
#pragma unroll
    for (int r = 0; r < 4; ++r) {
      int ub = r * 256 + w * 64;
      int u = ub + lane;
      int row = u >> 3, d = (u & 7) * 8;
      gload16(A + (size_t)(bm + row) * lda + k0 + d, aL + ub * 8);
      gload16(Bt + (size_t)(bn + row) * ldb + k0 + d, bL + ub * 8);
    }
    __syncthreads();
#pragma unroll
    for (int kc = 0; kc < 2; ++kc) {
      bf16x8 af[4], bfv[4];
#pragma unroll
      for (int i = 0; i < 4; ++i)
        af[i] = *(const bf16x8*)(aL + (wm + i * 16 + l15) * 64 + kc * 32 + g * 8);
#pragma unroll
      for (int j = 0; j < 4; ++j)
        bfv[j] = *(const bf16x8*)(bL + (wn + j * 16 + l15) * 64 + kc * 32 + g * 8);
#pragma unroll
      for (int i = 0; i < 4; ++i)
#pragma unroll
        for (int j = 0; j < 4; ++j)
          acc[i][j] = mfma16(af[i], bfv[j], acc[i][j]);
    }
  }
#pragma unroll
  for (int i = 0; i < 4; ++i) {
    int row = bm + wm + i * 16 + g * 4;
#pragma unroll
    for (int j = 0; j < 4; ++j) {
      int col = bn + wn + j * 16 + l15;
      float bc = biasCol ? biasCol[col] : 0.0f;
#pragma unroll
      for (int rr = 0; rr < 4; ++rr) {
        float br = biasRow ? biasRow[row + rr] : 0.0f;
        float v = acc[i][j][rr] + bc + br;
        if constexpr (sizeof(CT) == 2)
          C[(size_t)(row + rr) * ldc + col] = f2bf(v);
        else
          C[(size_t)(row + rr) * ldc + col] = v;
      }
    }
  }
}

// ---------------- fused mask + row softmax ----------------
// One wave per row of S [8192 rows x 2048]. Reads bf16 S + fp32 mask,
// writes normalized bf16 P. Scale (1/sqrt(1024))*log2(e) folded in here.
__global__ __launch_bounds__(256) void softmax_mask(
    const u16* __restrict__ S, const float* __restrict__ mask, u16* __restrict__ P) {
  const float C1 = 0.04508422f;    // log2(e)/32
  const float C2 = -1.4426950e9f;  // -1e9*log2(e)
  int wid = (blockIdx.x * blockDim.x + threadIdx.x) >> 6;  // global wave = row
  int lane = threadIdx.x & 63;
  size_t base = (size_t)wid * 2048;
  const u16* sp = S + base;
  const float* mp = mask + base;

  float a[32];
#pragma unroll
  for (int pass = 0; pass < 4; ++pass) {
    int e0 = pass * 512 + lane * 8;
    u16x8 sv = *(const u16x8*)(sp + e0);
    float4 m0 = *(const float4*)(mp + e0);
    float4 m1 = *(const float4*)(mp + e0 + 4);
    a[pass * 8 + 0] = bf2f(sv[0]) * C1 + m0.x * C2;
    a[pass * 8 + 1] = bf2f(sv[1]) * C1 + m0.y * C2;
    a[pass * 8 + 2] = bf2f(sv[2]) * C1 + m0.z * C2;
    a[pass * 8 + 3] = bf2f(sv[3]) * C1 + m0.w * C2;
    a[pass * 8 + 4] = bf2f(sv[4]) * C1 + m1.x * C2;
    a[pass * 8 + 5] = bf2f(sv[5]) * C1 + m1.y * C2;
    a[pass * 8 + 6] = bf2f(sv[6]) * C1 + m1.z * C2;
    a[pass * 8 + 7] = bf2f(sv[7]) * C1 + m1.w * C2;
  }
  float m = a[0];
#pragma unroll
  for (int i = 1; i < 32; ++i) m = fmaxf(m, a[i]);
#pragma unroll
  for (int off = 32; off >= 1; off >>= 1) m = fmaxf(m, __shfl_xor(m, off));

  float s = 0.0f;
#pragma unroll
  for (int i = 0; i < 32; ++i) {
    a[i] = exp2f(a[i] - m);
    s += a[i];
  }
#pragma unroll
  for (int off = 32; off >= 1; off >>= 1) s += __shfl_xor(s, off);
  float inv = 1.0f / s;

  u16* pp = P + base;
#pragma unroll
  for (int pass = 0; pass < 4; ++pass) {
    int e0 = pass * 512 + lane * 8;
    u16x8 o;
#pragma unroll
    for (int j = 0; j < 8; ++j) o[j] = f2bf(a[pass * 8 + j] * inv);
    *(u16x8*)(pp + e0) = o;
  }
}

extern "C" void kernel_launch(void* const* d_in, const int* in_sizes, int n_in,
                              void* d_out, int out_size, void* d_ws, size_t ws_size,
                              hipStream_t stream) {
  const float* primary = (const float*)d_in[0];
  const float* ctx     = (const float*)d_in[1];
  const float* mask    = (const float*)d_in[2];
  const float* Wq      = (const float*)d_in[3];
  const float* bq      = (const float*)d_in[4];
  const float* Wk      = (const float*)d_in[5];
  const float* bk      = (const float*)d_in[6];
  const float* Wv      = (const float*)d_in[7];
  const float* bv      = (const float*)d_in[8];
  float* out = (float*)d_out;

  char* ws = (char*)d_ws;
  // Live-range-aware layout (peak 90.2 MB, same as proven last round):
  //   [0, 16.7M)    qbf          (dead after S GEMM)   } P reuses [0, 33.5M)
  //   [16.7, 33.5M) kbf          (dead after S GEMM)   }
  //   [33.5, 50.3M) vtbf         (alive to the end)
  //   [50.3, 67M)   prim_bf      (dead after proj)     } S bf16 reuses
  //   [67, 83.9M)   ctx_bf       (dead after VT proj)  } [50.3, 83.9M)
  //   [83.9, 90.2M) wqt/wkt/wvt  (dead after proj)
  u16* qbf     = (u16*)(ws);
  u16* kbf     = (u16*)(ws + 16777216);
  u16* vtbf    = (u16*)(ws + 2 * 16777216);
  u16* prim_bf = (u16*)(ws + 3 * 16777216);
  u16* ctx_bf  = (u16*)(ws + 4 * 16777216);
  u16* wqt     = (u16*)(ws + 5 * 16777216);
  u16* wkt     = (u16*)(ws + 5 * 16777216 + 2097152);
  u16* wvt     = (u16*)(ws + 5 * 16777216 + 2 * 2097152);
  u16* sbf     = (u16*)(ws + 3 * 16777216);  // S bf16 overlays prim/ctx
  u16* pbf     = (u16*)(ws);                 // P bf16 overlays qbf/kbf

  cvt_f32_bf16<<<2048, 256, 0, stream>>>(primary, prim_bf, 8388608 / 4);
  cvt_f32_bf16<<<2048, 256, 0, stream>>>(ctx, ctx_bf, 8388608 / 4);
  wt_transpose<<<dim3(32, 32, 3), dim3(32, 8), 0, stream>>>(Wq, Wk, Wv, wqt, wkt, wvt);

  // Q = primary @ Wq + bq  -> qbf [8192 x 1024] bf16
  gemm_bt<u16><<<dim3(64, 8, 1), 256, 0, stream>>>(
      prim_bf, wqt, nullptr, bq, qbf, 8192, 1024, 1024, 1024, 1024, 1024, 0, 0, 0);
  // K = ctx @ Wk + bk      -> kbf [8192 x 1024] bf16
  gemm_bt<u16><<<dim3(64, 8, 1), 256, 0, stream>>>(
      ctx_bf, wkt, nullptr, bk, kbf, 8192, 1024, 1024, 1024, 1024, 1024, 0, 0, 0);
  // V^T = Wv^T @ ctx^T + bv (row bias) -> vtbf [1024 x 8192] bf16
  gemm_bt<u16><<<dim3(8, 64, 1), 256, 0, stream>>>(
      wvt, ctx_bf, bv, nullptr, vtbf, 1024, 8192, 1024, 1024, 1024, 8192, 0, 0, 0);
  // S = Q @ K^T (raw scores) -> sbf [4][2048 x 2048] bf16, batched
  gemm_bt<u16><<<dim3(16, 16, 4), 256, 0, stream>>>(
      qbf, kbf, nullptr, nullptr, sbf, 2048, 2048, 1024, 1024, 1024, 2048,
      2048 * 1024LL, 2048 * 1024LL, 2048 * 2048LL);
  // P = softmax(S*C1 + mask*C2), normalized -> pbf [4][2048 x 2048] bf16
  softmax_mask<<<2048, 256, 0, stream>>>(sbf, mask, pbf);
  // O = P @ V = P @ (V^T)^T -> out fp32 [4][2048 x 1024], batched
  gemm_bt<float><<<dim3(16, 8, 4), 256, 0, stream>>>(
      pbf, vtbf, nullptr, nullptr, out, 2048, 1024, 2048, 2048, 8192, 1024,
      2048 * 2048LL, 2048LL, 2048 * 1024LL);
}

// Round 4
// 240.609 us; speedup vs baseline: 2.4924x; 1.0995x over previous
//
#include <hip/hip_runtime.h>
#include <stdint.h>

typedef unsigned short u16;
typedef __bf16 bf16_t;
typedef bf16_t bf16x8 __attribute__((ext_vector_type(8)));
typedef float f32x4 __attribute__((ext_vector_type(4)));
typedef u16 u16x4 __attribute__((ext_vector_type(4)));
typedef u16 u16x8 __attribute__((ext_vector_type(8)));

__device__ __forceinline__ u16 f2bf(float f) {
  union { float f; uint32_t u; } v;
  v.f = f;
  uint32_t u = v.u + 0x7fffu + ((v.u >> 16) & 1u);
  return (u16)(u >> 16);
}

__device__ __forceinline__ float bf2f(u16 x) {
  union { uint32_t u; float f; } v;
  v.u = ((uint32_t)x) << 16;
  return v.f;
}

__device__ __forceinline__ void gload16(const void* g, void* l) {
  __builtin_amdgcn_global_load_lds(
      (__attribute__((address_space(1))) void*)g,
      (__attribute__((address_space(3))) void*)l, 16, 0, 0);
}

__device__ __forceinline__ f32x4 mfma16(bf16x8 a, bf16x8 b, f32x4 c) {
  return __builtin_amdgcn_mfma_f32_16x16x32_bf16(a, b, c, 0, 0, 0);
}

// ---------------- fp32 -> bf16 convert ----------------
__global__ void cvt_f32_bf16(const float* __restrict__ in, u16* __restrict__ out, int n4) {
  int i = blockIdx.x * blockDim.x + threadIdx.x;
  int stride = gridDim.x * blockDim.x;
  for (; i < n4; i += stride) {
    float4 v = *((const float4*)in + i);
    u16x4 o;
    o.x = f2bf(v.x); o.y = f2bf(v.y); o.z = f2bf(v.z); o.w = f2bf(v.w);
    *((u16x4*)out + i) = o;
  }
}

// ---------------- weight transpose + convert: Wt[n][k] = (bf16)W[k][n] ----------------
__global__ void wt_transpose(const float* __restrict__ Wq, const float* __restrict__ Wk,
                             const float* __restrict__ Wv, u16* __restrict__ Oq,
                             u16* __restrict__ Ok, u16* __restrict__ Ov) {
  const float* W = blockIdx.z == 0 ? Wq : (blockIdx.z == 1 ? Wk : Wv);
  u16* O = blockIdx.z == 0 ? Oq : (blockIdx.z == 1 ? Ok : Ov);
  __shared__ float t[32][33];
  int x = threadIdx.x, y = threadIdx.y;
  int n0 = blockIdx.x * 32, k0 = blockIdx.y * 32;
#pragma unroll
  for (int i = 0; i < 32; i += 8)
    t[y + i][x] = W[(size_t)(k0 + y + i) * 1024 + n0 + x];
  __syncthreads();
#pragma unroll
  for (int i = 0; i < 32; i += 8)
    O[(size_t)(n0 + y + i) * 1024 + k0 + x] = f2bf(t[x][y + i]);
}

// ---------------- 256x256 8-phase bf16 GEMM: C = A[M][K] * Bt[N][K]^T + bias ----------
// 512 threads = 8 waves (2M x 4N). BK=64, double-buffered LDS (128 KiB),
// 4 phases per K-tile: (Mhalf, Khalf) quadrants, 16 MFMA each.
// Sync invariant (fix for round-3 NaN race): counted vmcnt(N) is placed
// BEFORE the trailing s_barrier of ph2 (N=8) and ph4 (N=6), so every wave
// drains its share of a staged unit before any wave may ds_read it after
// the barrier. vmcnt never drains to 0 in the loop (3 units in flight).
template <typename CT>
__global__ __launch_bounds__(512, 2) void gemm256(
    const u16* __restrict__ A, const u16* __restrict__ Bt,
    const float* __restrict__ bc0, const float* __restrict__ bc1,
    const float* __restrict__ biasRow,
    CT* __restrict__ C, int K, int lda, int ldb, int ldc,
    long long bsA, long long bsB, long long bsC) {
  A += (size_t)blockIdx.z * bsA;
  Bt += (size_t)blockIdx.z * bsB;
  C += (size_t)blockIdx.z * bsC;
  const float* biasCol = (blockIdx.z == 1) ? bc1 : bc0;

  __shared__ u16 lds[2][2][256 * 64];  // [buf][op A=0/B=1][row*64 + col]
  int tid = threadIdx.x;
  int lane = tid & 63, w = tid >> 6;
  int l15 = lane & 15, g = lane >> 4;
  int wr = w >> 2, wc = w & 3;
  int bm = blockIdx.x * 256, bn = blockIdx.y * 256;
  int NT = K >> 6;

  f32x4 acc[8][4] = {};

  // stage A group h: rows h*64..+63 and h*64+128..+191 (2 loads/thread)
  auto stageA = [&](int buf, int h, int tk) {
    int k0 = tk * 64;
    int r = tid >> 3, cd = (tid & 7) * 8;
    int cs = cd ^ ((r & 7) * 8);
    int row0 = h * 64 + r;
    gload16(A + (size_t)(bm + row0) * lda + k0 + cs, &lds[buf][0][row0 * 64 + cd]);
    int row1 = row0 + 128;
    gload16(A + (size_t)(bm + row1) * lda + k0 + cs, &lds[buf][0][row1 * 64 + cd]);
  };
  // stage B half x: rows x*128..+127 (2 loads/thread)
  auto stageB = [&](int buf, int x, int tk) {
    int k0 = tk * 64;
#pragma unroll
    for (int l = 0; l < 2; ++l) {
      int u = l * 512 + tid;
      int r = u >> 3, cd = (u & 7) * 8;
      int cs = cd ^ ((r & 7) * 8);
      int row = x * 128 + r;
      gload16(Bt + (size_t)(bn + row) * ldb + k0 + cs, &lds[buf][1][row * 64 + cd]);
    }
  };
  auto ldA = [&](int buf, int m, int kc) -> bf16x8 {
    int row = wr * 128 + m * 16 + l15;
    int col = (kc * 32 + g * 8) ^ ((row & 7) * 8);
    return *(const bf16x8*)&lds[buf][0][row * 64 + col];
  };
  auto ldB = [&](int buf, int j, int kc) -> bf16x8 {
    int row = wc * 64 + j * 16 + l15;
    int col = (kc * 32 + g * 8) ^ ((row & 7) * 8);
    return *(const bf16x8*)&lds[buf][1][row * 64 + col];
  };

  // prologue: 6 units in issue order A0(0),B0(0),B1(0),A1(0),A0(1),B0(1)
  stageA(0, 0, 0);
  stageB(0, 0, 0);
  stageB(0, 1, 0);
  stageA(0, 1, 0);
  int t1c = NT > 1 ? 1 : 0;
  stageA(1, 0, t1c);
  stageB(1, 0, t1c);
  // drain the 3 units t0-ph1 consumes, then rendezvous so ALL waves' shares landed
  asm volatile("s_waitcnt vmcnt(6)" ::: "memory");
  __builtin_amdgcn_s_barrier();

  for (int t = 0; t < NT; ++t) {
    int cur = t & 1, nxt = cur ^ 1;
    int tn1 = (t + 1 < NT) ? t + 1 : NT - 1;
    int tn2 = (t + 2 < NT) ? t + 2 : NT - 1;
    bf16x8 a0[4], b0[4], b1[4];

    // ---- ph1: (Mhalf0, kc0) ----
#pragma unroll
    for (int i = 0; i < 4; ++i) a0[i] = ldA(cur, i, 0);
#pragma unroll
    for (int j = 0; j < 4; ++j) b0[j] = ldB(cur, j, 0);
    stageB(nxt, 1, tn1);
    __builtin_amdgcn_s_barrier();
    asm volatile("s_waitcnt lgkmcnt(0)" ::: "memory");
    __builtin_amdgcn_sched_barrier(0);
    __builtin_amdgcn_s_setprio(1);
#pragma unroll
    for (int i = 0; i < 4; ++i)
#pragma unroll
      for (int j = 0; j < 4; ++j) acc[i][j] = mfma16(a0[i], b0[j], acc[i][j]);
    __builtin_amdgcn_s_setprio(0);
    __builtin_amdgcn_s_barrier();

    // ---- ph2: (Mhalf0, kc1) ----
#pragma unroll
    for (int i = 0; i < 4; ++i) a0[i] = ldA(cur, i, 1);
#pragma unroll
    for (int j = 0; j < 4; ++j) b1[j] = ldB(cur, j, 1);
    stageA(nxt, 1, tn1);
    __builtin_amdgcn_s_barrier();
    asm volatile("s_waitcnt lgkmcnt(0)" ::: "memory");
    __builtin_amdgcn_sched_barrier(0);
    __builtin_amdgcn_s_setprio(1);
#pragma unroll
    for (int i = 0; i < 4; ++i)
#pragma unroll
      for (int j = 0; j < 4; ++j) acc[i][j] = mfma16(a0[i], b1[j], acc[i][j]);
    __builtin_amdgcn_s_setprio(0);
    // drain A1(t) (consumed next phase by all waves) BEFORE the barrier
    asm volatile("s_waitcnt vmcnt(8)" ::: "memory");
    __builtin_amdgcn_s_barrier();

    // ---- ph3: (Mhalf1, kc0) ----
#pragma unroll
    for (int i = 0; i < 4; ++i) a0[i] = ldA(cur, 4 + i, 0);
    stageA(cur, 0, tn2);
    __builtin_amdgcn_s_barrier();
    asm volatile("s_waitcnt lgkmcnt(0)" ::: "memory");
    __builtin_amdgcn_sched_barrier(0);
    __builtin_amdgcn_s_setprio(1);
#pragma unroll
    for (int i = 0; i < 4; ++i)
#pragma unroll
      for (int j = 0; j < 4; ++j) acc[4 + i][j] = mfma16(a0[i], b0[j], acc[4 + i][j]);
    __builtin_amdgcn_s_setprio(0);
    __builtin_amdgcn_s_barrier();

    // ---- ph4: (Mhalf1, kc1) ----
#pragma unroll
    for (int i = 0; i < 4; ++i) a0[i] = ldA(cur, 4 + i, 1);
    stageB(cur, 0, tn2);
    __builtin_amdgcn_s_barrier();
    asm volatile("s_waitcnt lgkmcnt(0)" ::: "memory");
    __builtin_amdgcn_sched_barrier(0);
    __builtin_amdgcn_s_setprio(1);
#pragma unroll
    for (int i = 0; i < 4; ++i)
#pragma unroll
      for (int j = 0; j < 4; ++j) acc[4 + i][j] = mfma16(a0[i], b1[j], acc[4 + i][j]);
    __builtin_amdgcn_s_setprio(0);
    // drain A0(t+1),B0(t+1),B1(t+1) (consumed at t+1 ph1) BEFORE the barrier
    asm volatile("s_waitcnt vmcnt(6)" ::: "memory");
    __builtin_amdgcn_s_barrier();
  }

  // epilogue
#pragma unroll
  for (int mi = 0; mi < 8; ++mi) {
    int row = bm + wr * 128 + mi * 16 + g * 4;
#pragma unroll
    for (int j = 0; j < 4; ++j) {
      int col = bn + wc * 64 + j * 16 + l15;
      float bcv = biasCol ? biasCol[col] : 0.0f;
#pragma unroll
      for (int rr = 0; rr < 4; ++rr) {
        float brv = biasRow ? biasRow[row + rr] : 0.0f;
        float v = acc[mi][j][rr] + bcv + brv;
        if constexpr (sizeof(CT) == 2)
          C[(size_t)(row + rr) * ldc + col] = f2bf(v);
        else
          C[(size_t)(row + rr) * ldc + col] = v;
      }
    }
  }
}

// ---------------- fused mask + row softmax ----------------
__global__ __launch_bounds__(256) void softmax_mask(
    const u16* __restrict__ S, const float* __restrict__ mask, u16* __restrict__ P) {
  const float C1 = 0.04508422f;    // log2(e)/32
  const float C2 = -1.4426950e9f;  // -1e9*log2(e)
  int wid = (blockIdx.x * blockDim.x + threadIdx.x) >> 6;  // global wave = row
  int lane = threadIdx.x & 63;
  size_t base = (size_t)wid * 2048;
  const u16* sp = S + base;
  const float* mp = mask + base;

  float a[32];
#pragma unroll
  for (int pass = 0; pass < 4; ++pass) {
    int e0 = pass * 512 + lane * 8;
    u16x8 sv = *(const u16x8*)(sp + e0);
    float4 m0 = *(const float4*)(mp + e0);
    float4 m1 = *(const float4*)(mp + e0 + 4);
    a[pass * 8 + 0] = bf2f(sv[0]) * C1 + m0.x * C2;
    a[pass * 8 + 1] = bf2f(sv[1]) * C1 + m0.y * C2;
    a[pass * 8 + 2] = bf2f(sv[2]) * C1 + m0.z * C2;
    a[pass * 8 + 3] = bf2f(sv[3]) * C1 + m0.w * C2;
    a[pass * 8 + 4] = bf2f(sv[4]) * C1 + m1.x * C2;
    a[pass * 8 + 5] = bf2f(sv[5]) * C1 + m1.y * C2;
    a[pass * 8 + 6] = bf2f(sv[6]) * C1 + m1.z * C2;
    a[pass * 8 + 7] = bf2f(sv[7]) * C1 + m1.w * C2;
  }
  float m = a[0];
#pragma unroll
  for (int i = 1; i < 32; ++i) m = fmaxf(m, a[i]);
#pragma unroll
  for (int off = 32; off >= 1; off >>= 1) m = fmaxf(m, __shfl_xor(m, off));

  float s = 0.0f;
#pragma unroll
  for (int i = 0; i < 32; ++i) {
    a[i] = exp2f(a[i] - m);
    s += a[i];
  }
#pragma unroll
  for (int off = 32; off >= 1; off >>= 1) s += __shfl_xor(s, off);
  float inv = 1.0f / s;

  u16* pp = P + base;
#pragma unroll
  for (int pass = 0; pass < 4; ++pass) {
    int e0 = pass * 512 + lane * 8;
    u16x8 o;
#pragma unroll
    for (int j = 0; j < 8; ++j) o[j] = f2bf(a[pass * 8 + j] * inv);
    *(u16x8*)(pp + e0) = o;
  }
}

extern "C" void kernel_launch(void* const* d_in, const int* in_sizes, int n_in,
                              void* d_out, int out_size, void* d_ws, size_t ws_size,
                              hipStream_t stream) {
  const float* primary = (const float*)d_in[0];
  const float* ctx     = (const float*)d_in[1];
  const float* mask    = (const float*)d_in[2];
  const float* Wq      = (const float*)d_in[3];
  const float* bq      = (const float*)d_in[4];
  const float* Wk      = (const float*)d_in[5];
  const float* bk      = (const float*)d_in[6];
  const float* Wv      = (const float*)d_in[7];
  const float* bv      = (const float*)d_in[8];
  float* out = (float*)d_out;

  char* ws = (char*)d_ws;
  // Layout (peak 90.2 MB):
  //   [0, 16.7M)    qbf      } P overlays [0, 33.5M)
  //   [16.7, 33.5M) kbf      }
  //   [33.5, 50.3M) vtbf
  //   [50.3, 67M)   prim_bf  } S bf16 overlays [50.3, 83.9M)
  //   [67, 83.9M)   ctx_bf   }  (prim_bf/ctx_bf contiguous: z-batched QK proj)
  //   [83.9, 90.2M) wqt/wkt/wvt (wqt/wkt contiguous: z-batched QK proj)
  u16* qbf     = (u16*)(ws);
  u16* kbf     = (u16*)(ws + 16777216);
  u16* vtbf    = (u16*)(ws + 2 * 16777216);
  u16* prim_bf = (u16*)(ws + 3 * 16777216);
  u16* ctx_bf  = (u16*)(ws + 4 * 16777216);
  u16* wqt     = (u16*)(ws + 5 * 16777216);
  u16* wkt     = (u16*)(ws + 5 * 16777216 + 2097152);
  u16* wvt     = (u16*)(ws + 5 * 16777216 + 2 * 2097152);
  u16* sbf     = (u16*)(ws + 3 * 16777216);
  u16* pbf     = (u16*)(ws);

  cvt_f32_bf16<<<2048, 256, 0, stream>>>(primary, prim_bf, 8388608 / 4);
  cvt_f32_bf16<<<2048, 256, 0, stream>>>(ctx, ctx_bf, 8388608 / 4);
  wt_transpose<<<dim3(32, 32, 3), dim3(32, 8), 0, stream>>>(Wq, Wk, Wv, wqt, wkt, wvt);

  // Q = primary @ Wq + bq ; K = ctx @ Wk + bk  (z-batched, 256 blocks)
  gemm256<u16><<<dim3(32, 4, 2), 512, 0, stream>>>(
      prim_bf, wqt, bq, bk, nullptr, qbf, 1024, 1024, 1024, 1024,
      8192 * 1024LL, 1024 * 1024LL, 8192 * 1024LL);
  // V^T = Wv^T @ ctx^T + bv (row bias) -> vtbf [1024 x 8192]
  gemm256<u16><<<dim3(4, 32, 1), 512, 0, stream>>>(
      wvt, ctx_bf, nullptr, nullptr, bv, vtbf, 1024, 1024, 1024, 8192, 0, 0, 0);
  // S = Q @ K^T -> sbf [4][2048 x 2048] bf16
  gemm256<u16><<<dim3(8, 8, 4), 512, 0, stream>>>(
      qbf, kbf, nullptr, nullptr, nullptr, sbf, 1024, 1024, 1024, 2048,
      2048 * 1024LL, 2048 * 1024LL, 2048 * 2048LL);
  // P = softmax(S*C1 + mask*C2) -> pbf
  softmax_mask<<<2048, 256, 0, stream>>>(sbf, mask, pbf);
  // O = P @ (V^T)^T -> out fp32 [4][2048 x 1024]
  gemm256<float><<<dim3(8, 4, 4), 512, 0, stream>>>(
      pbf, vtbf, nullptr, nullptr, nullptr, out, 2048, 2048, 8192, 1024,
      2048 * 2048LL, 2048LL, 2048 * 1024LL);
}